// Round 5
// baseline (128.000 us; speedup 1.0000x reference)
//
#include <hip/hip_runtime.h>
#include <hip/hip_bf16.h>

// BPTT diagonal RNN: u = X @ B^T, h_t = lam*h_{t-1} + u_t (chunked scan).
// R5 hybrid GEMM: B pre-converted to bf16 (small) and staged via global_load_lds
// (linear dest + inverse-swizzled global source); A (X, f32) reg-staged with
// 2-deep prefetch + fused cvt. One barrier per K=64 iter, counted vmcnt(8).

#define TDIM 8192
#define HDIM 2048
#define BM 256
#define BN 256
#define KT 64                  // K per iter
#define NIT (HDIM / KT)        // 32 iters
#define SLOT 16384             // shorts per LDS slot (256 rows x 64 k)
#define LCH 64                 // scan chunk length
#define GCH (TDIM / LCH)       // 128 chunks

#define BBF_BYTES (HDIM * HDIM * 2)   // 8 MB
#define E_BYTES   (GCH * HDIM * 4)    // 1 MB
#define WS_NEED   ((size_t)BBF_BYTES + E_BYTES)

typedef float f32x4 __attribute__((ext_vector_type(4)));
typedef short s16x8 __attribute__((ext_vector_type(8)));

static __device__ __forceinline__ short f2bf(float f) {
  __bf16 b = (__bf16)f;                 // RNE f32->bf16
  return __builtin_bit_cast(short, b);
}

#define SBAR()  asm volatile("s_barrier" ::: "memory")
#define VMW(n)  asm volatile("s_waitcnt vmcnt(" #n ")" ::: "memory")
#define LGKM0() asm volatile("s_waitcnt lgkmcnt(0)" ::: "memory")
#define SCHED0() __builtin_amdgcn_sched_barrier(0)
#define GLDS(gp, lp)                                                          \
  __builtin_amdgcn_global_load_lds(                                           \
      (const __attribute__((address_space(1))) void*)(gp),                    \
      (__attribute__((address_space(3))) void*)(lp), 16, 0, 0)

// ---------------- B: f32 -> bf16, natural row-major (exactly covers) --------
__global__ void cvt_B(const float* __restrict__ src, short* __restrict__ dst) {
  const int i = blockIdx.x * 256 + threadIdx.x;     // 0..524287
  f32x4 a = *(const f32x4*)(src + (size_t)i * 8);
  f32x4 b = *(const f32x4*)(src + (size_t)i * 8 + 4);
  s16x8 v;
  v[0] = f2bf(a[0]); v[1] = f2bf(a[1]); v[2] = f2bf(a[2]); v[3] = f2bf(a[3]);
  v[4] = f2bf(b[0]); v[5] = f2bf(b[1]); v[6] = f2bf(b[2]); v[7] = f2bf(b[3]);
  *(s16x8*)(dst + (size_t)i * 8) = v;
}

// ---------------- hybrid GEMM: U[t][j] = sum_k X[t][k] * B[j][k] ------------
// LDS rows = 64 shorts = 8 x 16B chunks; LDS(row, phys) holds k-chunk
// phys ^ (row&7). Frag reads use the XOR (verified 0-conflict in R4).
__global__ __launch_bounds__(512, 2) void gemm_hyb(
    const float* __restrict__ X, const short* __restrict__ Bb,
    float* __restrict__ U) {
  extern __shared__ __align__(16) short smem[];
  short* As = smem;              // 2 slots x 16384 shorts (64 KiB)
  short* Bs = smem + 2 * SLOT;   // 2 slots x 16384 shorts (64 KiB)

  // XCD-aware swizzle: nwg=256 (%8==0, bijective)
  const int wg  = blockIdx.x;
  const int swz = (wg & 7) * 32 + (wg >> 3);
  const int tm = swz >> 3;              // 0..31
  const int tn = swz & 7;               // 0..7
  const int row0 = tm * BM, col0 = tn * BN;

  const int tid  = threadIdx.x;
  const int lane = tid & 63;
  const int wid  = tid >> 6;
  const int wr = (wid >> 2) * 128;      // 2 m-groups
  const int wc = (wid & 3) * 64;        // 4 n-groups

  // fragment ds_read offsets (kh=0); kh=1 = offset ^ 32 shorts
  const int g4 = lane >> 4;
  int offA[8], offB[4];
#pragma unroll
  for (int m = 0; m < 8; ++m) {
    const int r = wr + m * 16 + (lane & 15);
    offA[m] = r * 64 + ((g4 ^ (r & 3)) << 3) + (((r >> 2) & 1) << 5);
  }
#pragma unroll
  for (int n = 0; n < 4; ++n) {
    const int r = wc + n * 16 + (lane & 15);
    offB[n] = r * 64 + ((g4 ^ (r & 3)) << 3) + (((r >> 2) & 1) << 5);
  }

  // staging: unit u = c*512 + tid -> LDS shorts [u*8, u*8+8) = (row=u>>3,
  // phys=u&7). Source chunk s_log = phys ^ (row&7); row = c*64 + (tid>>3).
  const int trow = tid >> 3;            // 0..63
  const int slog = (tid & 7) ^ (trow & 7);
  const float* gA = X  + (size_t)(row0 + trow) * HDIM + slog * 8;
  const short* gB = Bb + (size_t)(col0 + trow) * HDIM + slog * 8;

#define ISSUE_A(dst, t_) do {                                                 \
    _Pragma("unroll") for (int c = 0; c < 4; ++c) {                           \
      const float* p = gA + (size_t)c * 64 * HDIM + (t_) * KT;                \
      dst[2 * c]     = *(const f32x4*)p;                                      \
      dst[2 * c + 1] = *(const f32x4*)(p + 4);                                \
    }                                                                         \
  } while (0)

#define CVTWR_A(arr, sl) do {                                                 \
    _Pragma("unroll") for (int c = 0; c < 4; ++c) {                           \
      s16x8 v;                                                                \
      v[0] = f2bf(arr[2*c][0]); v[1] = f2bf(arr[2*c][1]);                     \
      v[2] = f2bf(arr[2*c][2]); v[3] = f2bf(arr[2*c][3]);                     \
      v[4] = f2bf(arr[2*c+1][0]); v[5] = f2bf(arr[2*c+1][1]);                 \
      v[6] = f2bf(arr[2*c+1][2]); v[7] = f2bf(arr[2*c+1][3]);                 \
      *(s16x8*)&As[(sl) * SLOT + (c * 512 + tid) * 8] = v;                    \
    }                                                                         \
  } while (0)

#define GLOADB(sl, t_) do {                                                   \
    _Pragma("unroll") for (int c = 0; c < 4; ++c)                             \
      GLDS(gB + (size_t)c * 64 * HDIM + (t_) * KT,                            \
           &Bs[(sl) * SLOT + (c * 512 + tid) * 8]);                           \
  } while (0)

#define PHASE(sl, khx) do {                                                   \
    s16x8 af[8], bfv[4];                                                      \
    _Pragma("unroll") for (int m = 0; m < 8; ++m)                             \
      af[m] = *(const s16x8*)&As[(sl) * SLOT + (offA[m] ^ (khx))];            \
    _Pragma("unroll") for (int n = 0; n < 4; ++n)                             \
      bfv[n] = *(const s16x8*)&Bs[(sl) * SLOT + (offB[n] ^ (khx))];           \
    __builtin_amdgcn_s_setprio(1);                                            \
    _Pragma("unroll") for (int m = 0; m < 8; ++m)                             \
      _Pragma("unroll") for (int n = 0; n < 4; ++n)                           \
        acc[m][n] = __builtin_amdgcn_mfma_f32_16x16x32_bf16(                  \
            af[m], bfv[n], acc[m][n], 0, 0, 0);                               \
    __builtin_amdgcn_s_setprio(0);                                            \
  } while (0)

  // iter i (cur=i&1): GLOADB(nxt,i+1); ISSUE(OTH,i+2); PHASE(cur,0);
  // CVTWR(CUR->nxt) [CUR holds tile i+1, issued at iter i-1]; PHASE(cur,32);
  // VMW(8) [drains the 4 B-gloads; A's 8 reg-loads may stay in flight];
  // LGKM0+SBAR.
#define ITER(cur, CUR, OTH, i_) do {                                          \
    GLOADB((cur) ^ 1, (i_) + 1);                                              \
    SCHED0();                                                                 \
    ISSUE_A(OTH, (i_) + 2);                                                   \
    PHASE(cur, 0);                                                            \
    CVTWR_A(CUR, (cur) ^ 1);                                                  \
    PHASE(cur, 32);                                                           \
    VMW(8);                                                                   \
    LGKM0();                                                                  \
    SBAR();                                                                   \
  } while (0)

  f32x4 acc[8][4] = {};
  f32x4 SA[8], SB[8];

  // prologue: slot0 = tile0 (A written, B loaded); SA = tile1 in flight
  ISSUE_A(SA, 0);
  GLOADB(0, 0);
  SCHED0();
  CVTWR_A(SA, 0);                       // auto-waits SA(tile0)
  ISSUE_A(SA, 1);
  VMW(8);                               // B(tile0) done; SA(tile1) in flight
  LGKM0();
  SBAR();

#pragma unroll 1
  for (int j = 0; j < NIT - 2; j += 2) {
    ITER(0, SA, SB, j);                 // computes tile j   (slot0)
    ITER(1, SB, SA, j + 1);             // computes tile j+1 (slot1)
  }
  // iter NIT-2 (even, cur=0): stage tile NIT-1 (SA holds its A regs)
  GLOADB(1, NIT - 1);
  PHASE(0, 0);
  CVTWR_A(SA, 1);
  PHASE(0, 32);
  VMW(0);
  LGKM0();
  SBAR();
  // iter NIT-1 (cur=1)
  PHASE(1, 0);
  PHASE(1, 32);

  // epilogue: C/D mapping col=lane&15, row=(lane>>4)*4+j [verified R1-R4]
  const int crow = row0 + wr + ((lane >> 4) << 2);
  const int ccol = col0 + wc + (lane & 15);
#pragma unroll
  for (int m = 0; m < 8; ++m)
#pragma unroll
    for (int n = 0; n < 4; ++n)
#pragma unroll
      for (int j = 0; j < 4; ++j)
        U[(size_t)(crow + m * 16 + j) * HDIM + ccol + n * 16] = acc[m][n][j];

#undef ISSUE_A
#undef CVTWR_A
#undef GLOADB
#undef PHASE
#undef ITER
}

// ---------------- fallback GEMM (R1-style, f32 reg-staging, proven) ---------
__global__ __launch_bounds__(256, 2) void gemm_f32_fb(
    const float* __restrict__ X, const float* __restrict__ Bm,
    float* __restrict__ U) {
#define LDK 40
#define FBM 128
#define FBK 32
#define FNT (HDIM / FBK)
  __shared__ __align__(16) short As[2][FBM * LDK];
  __shared__ __align__(16) short Bs[2][FBM * LDK];
  const int wg  = blockIdx.x;
  const int cpx = (TDIM / FBM) * (HDIM / FBM) / 8;
  const int swz = (wg & 7) * cpx + (wg >> 3);
  const int tm = swz >> 4;
  const int tn = swz & 15;
  const int row0 = tm * FBM, col0 = tn * FBM;
  const int tid  = threadIdx.x;
  const int lane = tid & 63;
  const int wid  = tid >> 6;
  const int wr = (wid >> 1) * 64;
  const int wc = (wid & 1) * 64;
  const int srow = tid >> 2;
  const int sk   = (tid & 3) << 3;
  const float* gA  = X  + (size_t)(row0 + srow) * HDIM + sk;
  const float* gA2 = gA + 64 * HDIM;
  const float* gB  = Bm + (size_t)(col0 + srow) * HDIM + sk;
  const float* gB2 = gB + 64 * HDIM;
  f32x4 a00, a01, a10, a11, b00, b01, b10, b11;
#define LOADREG(kt) do {                                                      \
    const float* p;                                                           \
    p = gA  + (kt) * FBK; a00 = *(const f32x4*)p; a01 = *(const f32x4*)(p+4); \
    p = gA2 + (kt) * FBK; a10 = *(const f32x4*)p; a11 = *(const f32x4*)(p+4); \
    p = gB  + (kt) * FBK; b00 = *(const f32x4*)p; b01 = *(const f32x4*)(p+4); \
    p = gB2 + (kt) * FBK; b10 = *(const f32x4*)p; b11 = *(const f32x4*)(p+4); \
  } while (0)
#define CVT8(v, lo, hi) do {                                                  \
    v[0] = f2bf(lo[0]); v[1] = f2bf(lo[1]); v[2] = f2bf(lo[2]);               \
    v[3] = f2bf(lo[3]); v[4] = f2bf(hi[0]); v[5] = f2bf(hi[1]);               \
    v[6] = f2bf(hi[2]); v[7] = f2bf(hi[3]);                                   \
  } while (0)
#define DSWRITE(buf) do {                                                     \
    s16x8 v;                                                                  \
    CVT8(v, a00, a01); *(s16x8*)&As[buf][srow * LDK + sk] = v;                \
    CVT8(v, a10, a11); *(s16x8*)&As[buf][(srow + 64) * LDK + sk] = v;         \
    CVT8(v, b00, b01); *(s16x8*)&Bs[buf][srow * LDK + sk] = v;                \
    CVT8(v, b10, b11); *(s16x8*)&Bs[buf][(srow + 64) * LDK + sk] = v;         \
  } while (0)
  f32x4 acc[4][4] = {};
#define COMPUTE(buf) do {                                                     \
    const int r16_ = lane & 15;                                               \
    const int ks_  = (lane >> 4) * 8;                                         \
    s16x8 af[4], bfr[4];                                                      \
    _Pragma("unroll") for (int m = 0; m < 4; ++m)                             \
      af[m] = *(const s16x8*)&As[buf][(wr + m * 16 + r16_) * LDK + ks_];      \
    _Pragma("unroll") for (int n = 0; n < 4; ++n)                             \
      bfr[n] = *(const s16x8*)&Bs[buf][(wc + n * 16 + r16_) * LDK + ks_];     \
    _Pragma("unroll") for (int m = 0; m < 4; ++m)                             \
      _Pragma("unroll") for (int n = 0; n < 4; ++n)                           \
        acc[m][n] = __builtin_amdgcn_mfma_f32_16x16x32_bf16(                  \
            af[m], bfr[n], acc[m][n], 0, 0, 0);                               \
  } while (0)
  LOADREG(0);
  DSWRITE(0);
  __syncthreads();
#pragma unroll 2
  for (int kt = 0; kt < FNT; ++kt) {
    const int cur = kt & 1;
    if (kt + 1 < FNT) LOADREG(kt + 1);
    COMPUTE(cur);
    if (kt + 1 < FNT) DSWRITE(cur ^ 1);
    __syncthreads();
  }
  const int crow = wr + ((lane >> 4) << 2);
  const int ccol = wc + (lane & 15);
#pragma unroll
  for (int m = 0; m < 4; ++m)
#pragma unroll
    for (int n = 0; n < 4; ++n)
#pragma unroll
      for (int j = 0; j < 4; ++j)
        U[(size_t)(row0 + crow + m * 16 + j) * HDIM + (col0 + ccol + n * 16)] =
            acc[m][n][j];
#undef LOADREG
#undef CVT8
#undef DSWRITE
#undef COMPUTE
#undef LDK
#undef FBM
#undef FBK
#undef FNT
}

// ---------------- scan pass 1: per-chunk local scan end values ---------------
__global__ void scan_pass1(const float* __restrict__ U,
                           const float* __restrict__ lam,
                           float* __restrict__ e) {
  const int c = (blockIdx.y * 256 + threadIdx.x) * 4;
  const int j = blockIdx.x;
  const f32x4 l4 = *(const f32x4*)&lam[c];
  f32x4 h = {0.f, 0.f, 0.f, 0.f};
  const float* up = U + (size_t)j * LCH * HDIM + c;
#pragma unroll 4
  for (int t = 0; t < LCH; ++t) {
    f32x4 u4 = *(const f32x4*)up;
    h = l4 * h + u4;
    up += HDIM;
  }
  *(f32x4*)&e[(size_t)j * HDIM + c] = h;
}

// ---------------- scan pass 2: carry scan over chunks (in-place on e) --------
__global__ void scan_carry(float* __restrict__ e, const float* __restrict__ lam) {
  const int c = (blockIdx.x * 256 + threadIdx.x) * 4;
  const f32x4 l4 = *(const f32x4*)&lam[c];
  f32x4 p = l4;
#pragma unroll
  for (int i = 0; i < 6; ++i) p = p * p;   // lam^64
  f32x4 E = {0.f, 0.f, 0.f, 0.f};
  for (int j = 0; j < GCH; ++j) {
    f32x4 ej = *(const f32x4*)&e[(size_t)j * HDIM + c];
    *(f32x4*)&e[(size_t)j * HDIM + c] = E;  // carry into chunk j = E_{j-1}
    E = p * E + ej;
  }
}

// ---------------- scan pass 3: final scan with carry, in-place U -> h --------
__global__ void scan_pass3(float* __restrict__ U, const float* __restrict__ lam,
                           const float* __restrict__ carry) {
  const int c = (blockIdx.y * 256 + threadIdx.x) * 4;
  const int j = blockIdx.x;
  const f32x4 l4 = *(const f32x4*)&lam[c];
  f32x4 h = *(const f32x4*)&carry[(size_t)j * HDIM + c];
  float* up = U + (size_t)j * LCH * HDIM + c;
#pragma unroll 4
  for (int t = 0; t < LCH; ++t) {
    f32x4 u4 = *(const f32x4*)up;
    h = l4 * h + u4;
    *(f32x4*)up = h;
    up += HDIM;
  }
}

extern "C" void kernel_launch(void* const* d_in, const int* in_sizes, int n_in,
                              void* d_out, int out_size, void* d_ws, size_t ws_size,
                              hipStream_t stream) {
  const float* X   = (const float*)d_in[0];
  const float* lam = (const float*)d_in[1];
  const float* Bm  = (const float*)d_in[2];
  float* U = (float*)d_out;              // u then h, in-place

  if (ws_size >= WS_NEED) {
    short* Bb = (short*)d_ws;
    float* e  = (float*)((char*)d_ws + BBF_BYTES);

    hipFuncSetAttribute((const void*)gemm_hyb,
                        hipFuncAttributeMaxDynamicSharedMemorySize, 131072);

    cvt_B<<<dim3(HDIM * HDIM / (8 * 256)), dim3(256), 0, stream>>>(Bm, Bb);
    gemm_hyb<<<dim3((TDIM / BM) * (HDIM / BN)), dim3(512), 131072, stream>>>(
        X, Bb, U);
    scan_pass1<<<dim3(GCH, HDIM / 1024), dim3(256), 0, stream>>>(U, lam, e);
    scan_carry<<<dim3(HDIM / 1024), dim3(256), 0, stream>>>(e, lam);
    scan_pass3<<<dim3(GCH, HDIM / 1024), dim3(256), 0, stream>>>(U, lam, e);
  } else {
    float* e = (float*)d_ws;
    gemm_f32_fb<<<dim3((TDIM / 128) * (HDIM / 128)), dim3(256), 0, stream>>>(
        X, Bm, U);
    scan_pass1<<<dim3(GCH, HDIM / 1024), dim3(256), 0, stream>>>(U, lam, e);
    scan_carry<<<dim3(HDIM / 1024), dim3(256), 0, stream>>>(e, lam);
    scan_pass3<<<dim3(GCH, HDIM / 1024), dim3(256), 0, stream>>>(U, lam, e);
  }
}

// Round 6
// 124.162 us; speedup vs baseline: 1.0309x; 1.0309x over previous
//
#include <hip/hip_runtime.h>
#include <hip/hip_bf16.h>

// BPTT diagonal RNN: u = X @ B^T, h_t = lam*h_{t-1} + u_t (chunked scan).
// R6: fused GEMM (f32 in, reg-staged cvt->LDS) with T14 schedule:
// per iter {issue 16 loads -> 64 MFMA -> cvt+ds_write -> lgkm0 + raw barrier}.
// Loads age the full MFMA block (~620cy) before consumption -> no in-stream
// vmcnt stalls. BK=64 XOR swizzle (0 conflicts, verified R4). No cvt pass.

#define TDIM 8192
#define HDIM 2048
#define BM 256
#define BN 256
#define KT 64                  // K per iter (floats)
#define NIT (HDIM / KT)        // 32 iters
#define SLOT 16384             // shorts per LDS slot (256 rows x 64 k)
#define LCH 64                 // scan chunk length
#define GCH (TDIM / LCH)       // 128 chunks

typedef float f32x4 __attribute__((ext_vector_type(4)));
typedef short s16x4 __attribute__((ext_vector_type(4)));
typedef short s16x8 __attribute__((ext_vector_type(8)));

static __device__ __forceinline__ short f2bf(float f) {
  __bf16 b = (__bf16)f;                 // RNE f32->bf16
  return __builtin_bit_cast(short, b);
}

#define SBAR()   asm volatile("s_barrier" ::: "memory")
#define LGKM0()  asm volatile("s_waitcnt lgkmcnt(0)" ::: "memory")
#define SCHED0() __builtin_amdgcn_sched_barrier(0)

// ---------------- fused GEMM: U[t][j] = sum_k X[t][k] * Bm[j][k] ------------
// 8 waves (2Mx4N), per-wave out 128x64 (8m x 4n frags of 16x16).
// LDS rows = 64 shorts (128B) = 8 x 16B chunks; phys chunk = logical ^ (row&7)
// -> conflict-free ds_read_b128 frags AND conflict-free ds_write staging.
__global__ __launch_bounds__(512, 2) void gemm_fused2(
    const float* __restrict__ X, const float* __restrict__ Bm,
    float* __restrict__ U) {
  extern __shared__ __align__(16) short smem[];
  short* As = smem;              // 2 slots x 16384 shorts (64 KiB)
  short* Bs = smem + 2 * SLOT;   // 2 slots x 16384 shorts (64 KiB)

  // XCD-aware swizzle: nwg=256 (%8==0, bijective)
  const int wg  = blockIdx.x;
  const int swz = (wg & 7) * 32 + (wg >> 3);
  const int tm = swz >> 3;              // 0..31
  const int tn = swz & 7;               // 0..7
  const int row0 = tm * BM, col0 = tn * BN;

  const int tid  = threadIdx.x;
  const int lane = tid & 63;
  const int wid  = tid >> 6;
  const int wr = (wid >> 2) * 128;      // 2 m-groups
  const int wc = (wid & 3) * 64;        // 4 n-groups

  // fragment ds_read offsets (kh=0); kh=1 = offset ^ 32 shorts
  const int g4 = lane >> 4;
  int offA[8], offB[4];
#pragma unroll
  for (int m = 0; m < 8; ++m) {
    const int r = wr + m * 16 + (lane & 15);
    offA[m] = r * 64 + ((g4 ^ (r & 3)) << 3) + (((r >> 2) & 1) << 5);
  }
#pragma unroll
  for (int n = 0; n < 4; ++n) {
    const int r = wc + n * 16 + (lane & 15);
    offB[n] = r * 64 + ((g4 ^ (r & 3)) << 3) + (((r >> 2) & 1) << 5);
  }

  // staging: load c in 0..7: row = (tid>>4) + c*32, floats [(tid&15)*4, +4)
  const int lrow   = tid >> 4;          // 0..31
  const int lcol16 = (tid & 15) * 4;    // float col within tile k-window
  const float* gA = X  + (size_t)(row0 + lrow) * HDIM + lcol16;
  const float* gB = Bm + (size_t)(col0 + lrow) * HDIM + lcol16;

  // ds_write (b64) offsets: wrow=lrow+c*32, chunk=(tid&15)>>1, half=tid&1
  int offW[8];
#pragma unroll
  for (int c = 0; c < 8; ++c) {
    const int wrow = lrow + c * 32;
    offW[c] = wrow * 64 + ((((tid & 15) >> 1) ^ (wrow & 7)) << 3) + (tid & 1) * 4;
  }

#define ISSUE(dst, gp, t_) do {                                               \
    _Pragma("unroll") for (int c = 0; c < 8; ++c)                             \
      dst[c] = *(const f32x4*)((gp) + (size_t)c * 32 * HDIM + (t_) * KT);     \
  } while (0)

#define CVTWR(arr, base, sl) do {                                             \
    _Pragma("unroll") for (int c = 0; c < 8; ++c) {                           \
      s16x4 v;                                                                \
      v[0] = f2bf(arr[c][0]); v[1] = f2bf(arr[c][1]);                         \
      v[2] = f2bf(arr[c][2]); v[3] = f2bf(arr[c][3]);                         \
      *(s16x4*)&base[(sl) * SLOT + offW[c]] = v;                              \
    }                                                                         \
  } while (0)

#define PHASE(sl, khx) do {                                                   \
    s16x8 af[8], bfv[4];                                                      \
    _Pragma("unroll") for (int m = 0; m < 8; ++m)                             \
      af[m] = *(const s16x8*)&As[(sl) * SLOT + (offA[m] ^ (khx))];            \
    _Pragma("unroll") for (int n = 0; n < 4; ++n)                             \
      bfv[n] = *(const s16x8*)&Bs[(sl) * SLOT + (offB[n] ^ (khx))];           \
    __builtin_amdgcn_s_setprio(1);                                            \
    _Pragma("unroll") for (int m = 0; m < 8; ++m)                             \
      _Pragma("unroll") for (int n = 0; n < 4; ++n)                           \
        acc[m][n] = __builtin_amdgcn_mfma_f32_16x16x32_bf16(                  \
            af[m], bfv[n], acc[m][n], 0, 0, 0);                               \
    __builtin_amdgcn_s_setprio(0);                                            \
  } while (0)

  f32x4 acc[8][4] = {};
  f32x4 ra[8], rb[8];

  // prologue: tile 0 -> slot 0 (consume immediately; one-time stall)
  ISSUE(ra, gA, 0);
  ISSUE(rb, gB, 0);
  CVTWR(ra, As, 0);
  CVTWR(rb, Bs, 0);
  LGKM0();
  SBAR();

#pragma unroll 1
  for (int j = 0; j < NIT - 1; ++j) {
    const int cur = j & 1;
    ISSUE(ra, gA, j + 1);               // 8 A loads (oldest)
    ISSUE(rb, gB, j + 1);               // 8 B loads
    SCHED0();                           // pin loads before the MFMA block
    PHASE(cur, 0);                      // 12 ds_read + 32 MFMA
    PHASE(cur, 32);                     // 12 ds_read + 32 MFMA (~620cy total)
    CVTWR(ra, As, cur ^ 1);             // loads aged ~620cy -> ~no vmcnt stall
    CVTWR(rb, Bs, cur ^ 1);
    LGKM0();                            // ds_writes visible
    SBAR();                             // no vmcnt(0) drain (raw barrier)
  }
  {
    const int cur = (NIT - 1) & 1;
    PHASE(cur, 0);
    PHASE(cur, 32);
  }

  // epilogue: C/D mapping col=lane&15, row=(lane>>4)*4+j [verified R1-R5]
  const int crow = row0 + wr + ((lane >> 4) << 2);
  const int ccol = col0 + wc + (lane & 15);
#pragma unroll
  for (int m = 0; m < 8; ++m)
#pragma unroll
    for (int n = 0; n < 4; ++n)
#pragma unroll
      for (int j = 0; j < 4; ++j)
        U[(size_t)(crow + m * 16 + j) * HDIM + ccol + n * 16] = acc[m][n][j];

#undef ISSUE
#undef CVTWR
#undef PHASE
}

// ---------------- scan pass 1: per-chunk local scan end values ---------------
__global__ void scan_pass1(const float* __restrict__ U,
                           const float* __restrict__ lam,
                           float* __restrict__ e) {
  const int c = (blockIdx.y * 256 + threadIdx.x) * 4;
  const int j = blockIdx.x;
  const f32x4 l4 = *(const f32x4*)&lam[c];
  f32x4 h = {0.f, 0.f, 0.f, 0.f};
  const float* up = U + (size_t)j * LCH * HDIM + c;
#pragma unroll 4
  for (int t = 0; t < LCH; ++t) {
    f32x4 u4 = *(const f32x4*)up;
    h = l4 * h + u4;
    up += HDIM;
  }
  *(f32x4*)&e[(size_t)j * HDIM + c] = h;
}

// ---------------- scan pass 2: carry scan over chunks (in-place on e) --------
__global__ void scan_carry(float* __restrict__ e, const float* __restrict__ lam) {
  const int c = (blockIdx.x * 256 + threadIdx.x) * 4;
  const f32x4 l4 = *(const f32x4*)&lam[c];
  f32x4 p = l4;
#pragma unroll
  for (int i = 0; i < 6; ++i) p = p * p;   // lam^64
  f32x4 E = {0.f, 0.f, 0.f, 0.f};
  for (int j = 0; j < GCH; ++j) {
    f32x4 ej = *(const f32x4*)&e[(size_t)j * HDIM + c];
    *(f32x4*)&e[(size_t)j * HDIM + c] = E;  // carry into chunk j = E_{j-1}
    E = p * E + ej;
  }
}

// ---------------- scan pass 3: final scan with carry, in-place U -> h --------
__global__ void scan_pass3(float* __restrict__ U, const float* __restrict__ lam,
                           const float* __restrict__ carry) {
  const int c = (blockIdx.y * 256 + threadIdx.x) * 4;
  const int j = blockIdx.x;
  const f32x4 l4 = *(const f32x4*)&lam[c];
  f32x4 h = *(const f32x4*)&carry[(size_t)j * HDIM + c];
  float* up = U + (size_t)j * LCH * HDIM + c;
#pragma unroll 4
  for (int t = 0; t < LCH; ++t) {
    f32x4 u4 = *(const f32x4*)up;
    h = l4 * h + u4;
    *(f32x4*)up = h;
    up += HDIM;
  }
}

extern "C" void kernel_launch(void* const* d_in, const int* in_sizes, int n_in,
                              void* d_out, int out_size, void* d_ws, size_t ws_size,
                              hipStream_t stream) {
  const float* X   = (const float*)d_in[0];
  const float* lam = (const float*)d_in[1];
  const float* Bm  = (const float*)d_in[2];
  float* U = (float*)d_out;              // u then h, in-place
  float* e = (float*)d_ws;               // 1 MB chunk carries

  // allow 128 KiB dynamic LDS (host-side, idempotent, capture-safe: proven R3+)
  hipFuncSetAttribute((const void*)gemm_fused2,
                      hipFuncAttributeMaxDynamicSharedMemorySize, 131072);

  gemm_fused2<<<dim3((TDIM / BM) * (HDIM / BN)), dim3(512), 131072, stream>>>(
      X, Bm, U);
  scan_pass1<<<dim3(GCH, HDIM / 1024), dim3(256), 0, stream>>>(U, lam, e);
  scan_carry<<<dim3(HDIM / 1024), dim3(256), 0, stream>>>(e, lam);
  scan_pass3<<<dim3(GCH, HDIM / 1024), dim3(256), 0, stream>>>(U, lam, e);
}